// Round 16
// baseline (147.520 us; speedup 1.0000x reference)
//
#include <hip/hip_runtime.h>
#include <math.h>

#define IMG_H 512
#define IMG_W 512
#define N_IMG 96            // 32 * 3
#define TW 32               // tile width (output cols)
#define TH 64               // tile height (output rows)
#define KS 11
#define IN_ROWS 74          // TH + 10
#define NUNITS (IN_ROWS * 8)    // 592 horizontal-conv units (4 px each)
#define STRIDE 33           // LDS row stride in float2 units
#define PLANE (IN_ROWS * STRIDE)   // 2442 float2
#define NBLOCKS (N_IMG * (IMG_W / TW) * (IMG_H / TH))   // 12288
#define TOTAL_N 25165824.0  // 32*3*512*512

// Round-15 (resubmit; infra failure): deepen memory-level parallelism per
// wave. r14 falsified the CP-dispatch-rate wall (rate fell to 82 WG/us when
// demand dropped); the invariant across r11/r12/r14 is ~2 TB/s fetch +
// true-VALU ~28% (gfx94x VALUBusy formula overstates 2x on SIMD-32) ->
// waves stall ~90% on memory latency; stage 1's 2-3 sequential
// {load-batch -> wait -> compute} unit iterations serialize ~3 HBM round
// trips per wave.
// Fix: HOIST units 0+1's 20 float4 loads into one issue burst (raw in regs),
// then transform+convolve both. Unit 2 (tid<80) unchanged. Boundary threads
// use the elementwise fallback. ~100 VGPR peak, (256,4) cap 128.

#define GW(j) g6[(j) <= 5 ? (j) : 10 - (j)]

// convolve uw/vw (squared in place) and store 4 px at wb
#define CONV_STORE(UW, VW, WB) do {                                          \
    float au_[4], av_[4], auu_[4], avv_[4];                                  \
    _Pragma("unroll") for (int k = 0; k < 4; ++k) { au_[k]=0.f; av_[k]=0.f; }\
    _Pragma("unroll") for (int k = 0; k < 4; ++k) {                          \
        _Pragma("unroll") for (int j = 0; j < KS; ++j) {                     \
            au_[k] = fmaf(GW(j), UW[k + j], au_[k]);                         \
            av_[k] = fmaf(GW(j), VW[k + j], av_[k]);                         \
        }                                                                    \
    }                                                                        \
    _Pragma("unroll") for (int i = 0; i < 14; ++i) { UW[i]*=UW[i]; VW[i]*=VW[i]; } \
    _Pragma("unroll") for (int k = 0; k < 4; ++k) { auu_[k]=0.f; avv_[k]=0.f; }    \
    _Pragma("unroll") for (int k = 0; k < 4; ++k) {                          \
        _Pragma("unroll") for (int j = 0; j < KS; ++j) {                     \
            auu_[k] = fmaf(GW(j), UW[k + j], auu_[k]);                       \
            avv_[k] = fmaf(GW(j), VW[k + j], avv_[k]);                       \
        }                                                                    \
    }                                                                        \
    _Pragma("unroll") for (int e = 0; e < 4; ++e) {                          \
        Hu[(WB) + e] = make_float2(au_[e], auu_[e]);                         \
        Hv[(WB) + e] = make_float2(av_[e], avv_[e]);                         \
    }                                                                        \
} while (0)

// per-unit fast gather (interior window), r12-style
#define PROC_UNIT_FAST(RP, RT, COL0, WB) do {                                \
    float uw_[14], vw_[14];                                                  \
    _Pragma("unroll") for (int q = 0; q < 5; ++q) {                          \
        const float4 vp_ = *(const float4*)((RP) + (COL0) + 4 * q);          \
        const float4 vt_ = *(const float4*)((RT) + (COL0) + 4 * q);          \
        const float pe_[4] = {vp_.x, vp_.y, vp_.z, vp_.w};                   \
        const float te_[4] = {vt_.x, vt_.y, vt_.z, vt_.w};                   \
        _Pragma("unroll") for (int e = 0; e < 4; ++e) {                      \
            const int ge_ = 4 * q + e;                                       \
            if (ge_ >= 3 && ge_ <= 16) {                                     \
                uw_[ge_ - 3] = pe_[e] + te_[e];                              \
                vw_[ge_ - 3] = pe_[e] - te_[e];                              \
            }                                                                \
        }                                                                    \
    }                                                                        \
    CONV_STORE(uw_, vw_, (WB));                                              \
} while (0)

// per-unit elementwise gather (boundary-safe)
#define PROC_UNIT_EW(RP, RT, COL0, ROWOK, WB) do {                           \
    float uw_[14], vw_[14];                                                  \
    _Pragma("unroll") for (int e = 3; e <= 16; ++e) {                        \
        const int c_  = (COL0) + e;                                          \
        const int cc_ = min(max(c_, 0), IMG_W - 1);                          \
        const bool ok_ = (ROWOK) && (c_ >= 0) && (c_ < IMG_W);               \
        const float pv_ = (RP)[cc_];                                         \
        const float tv_ = (RT)[cc_];                                         \
        uw_[e - 3] = ok_ ? (pv_ + tv_) : 0.0f;                               \
        vw_[e - 3] = ok_ ? (pv_ - tv_) : 0.0f;                               \
    }                                                                        \
    CONV_STORE(uw_, vw_, (WB));                                              \
} while (0)

__global__ __launch_bounds__(256, 4) void ssim_tile_kernel(
    const float* __restrict__ pred, const float* __restrict__ targ,
    const float* __restrict__ k2d, float* __restrict__ partial)
{
    __shared__ float2 Hu[PLANE];
    __shared__ float2 Hv[PLANE];
    __shared__ float wsum[4];

    const int tid = threadIdx.x;
    const int bid = blockIdx.x;
    const int img = bid >> 7;          // 128 tiles per image
    const int tin = bid & 127;
    const int ty  = tin >> 4;          // 0..7
    const int tx  = tin & 15;          // 0..15
    const int y0  = ty * TH;
    const int x0  = tx * TW;

    // exact 1D gaussian from the 2D kernel row 5: k2d[5][j] = g5*g[j]; symmetric
    float g6[6];
    {
        const float inv = rsqrtf(k2d[5 * KS + 5]);
        #pragma unroll
        for (int j = 0; j < 6; ++j) g6[j] = k2d[5 * KS + j] * inv;
    }

    const float* __restrict__ Pimg = pred + (size_t)img * (IMG_H * IMG_W);
    const float* __restrict__ Timg = targ + (size_t)img * (IMG_H * IMG_W);

    // ---- stage 1: horizontal 11-tap on u,v,u^2,v^2 -> packed LDS planes ----
    // unit geometry for u0=tid, u1=tid+256 (both always < NUNITS=592)
    const int r0   = tid >> 3,            cg0 = tid & 7;
    const int u1i  = tid + 256;
    const int r1   = u1i >> 3,            cg1 = u1i & 7;
    const int gr0  = y0 - 5 + r0,         gr1 = y0 - 5 + r1;
    const int col00 = x0 + (cg0 << 2) - 8;
    const int col01 = x0 + (cg1 << 2) - 8;
    const bool rowok0 = ((unsigned)gr0 < (unsigned)IMG_H);
    const bool rowok1 = ((unsigned)gr1 < (unsigned)IMG_H);
    const float* rowP0 = Pimg + (size_t)(rowok0 ? gr0 : 0) * IMG_W;
    const float* rowT0 = Timg + (size_t)(rowok0 ? gr0 : 0) * IMG_W;
    const float* rowP1 = Pimg + (size_t)(rowok1 ? gr1 : 0) * IMG_W;
    const float* rowT1 = Timg + (size_t)(rowok1 ? gr1 : 0) * IMG_W;
    const bool fast0 = rowok0 && (col00 >= 0) && (col00 + 20 <= IMG_W);
    const bool fast1 = rowok1 && (col01 >= 0) && (col01 + 20 <= IMG_W);
    const int wb0 = r0 * STRIDE + (cg0 << 2);
    const int wb1 = r1 * STRIDE + (cg1 << 2);

    if (fast0 && fast1) {
        // HOISTED path: issue all 20 loads before any compute
        float4 p0[5], t0[5], p1[5], t1[5];
        #pragma unroll
        for (int q = 0; q < 5; ++q) {
            p0[q] = *(const float4*)(rowP0 + col00 + 4 * q);
            t0[q] = *(const float4*)(rowT0 + col00 + 4 * q);
        }
        #pragma unroll
        for (int q = 0; q < 5; ++q) {
            p1[q] = *(const float4*)(rowP1 + col01 + 4 * q);
            t1[q] = *(const float4*)(rowT1 + col01 + 4 * q);
        }

        // unit 0: transform + convolve + store
        {
            float uw0[14], vw0[14];
            #pragma unroll
            for (int q = 0; q < 5; ++q) {
                const float pe[4] = {p0[q].x, p0[q].y, p0[q].z, p0[q].w};
                const float te[4] = {t0[q].x, t0[q].y, t0[q].z, t0[q].w};
                #pragma unroll
                for (int e = 0; e < 4; ++e) {
                    const int ge = 4 * q + e;
                    if (ge >= 3 && ge <= 16) {
                        uw0[ge - 3] = pe[e] + te[e];
                        vw0[ge - 3] = pe[e] - te[e];
                    }
                }
            }
            CONV_STORE(uw0, vw0, wb0);
        }
        // unit 1 (its loads were in flight during unit 0's compute)
        {
            float uw1[14], vw1[14];
            #pragma unroll
            for (int q = 0; q < 5; ++q) {
                const float pe[4] = {p1[q].x, p1[q].y, p1[q].z, p1[q].w};
                const float te[4] = {t1[q].x, t1[q].y, t1[q].z, t1[q].w};
                #pragma unroll
                for (int e = 0; e < 4; ++e) {
                    const int ge = 4 * q + e;
                    if (ge >= 3 && ge <= 16) {
                        uw1[ge - 3] = pe[e] + te[e];
                        vw1[ge - 3] = pe[e] - te[e];
                    }
                }
            }
            CONV_STORE(uw1, vw1, wb1);
        }
    } else {
        if (fast0) PROC_UNIT_FAST(rowP0, rowT0, col00, wb0);
        else       PROC_UNIT_EW(rowP0, rowT0, col00, rowok0, wb0);
        if (fast1) PROC_UNIT_FAST(rowP1, rowT1, col01, wb1);
        else       PROC_UNIT_EW(rowP1, rowT1, col01, rowok1, wb1);
    }

    // unit 2: only threads 0..79 (rows 64..73)
    if (tid < 80) {
        const int u2i = tid + 512;
        const int r2 = u2i >> 3, cg2 = u2i & 7;
        const int gr2 = y0 - 5 + r2;
        const int col02 = x0 + (cg2 << 2) - 8;
        const bool rowok2 = ((unsigned)gr2 < (unsigned)IMG_H);
        const float* rowP2 = Pimg + (size_t)(rowok2 ? gr2 : 0) * IMG_W;
        const float* rowT2 = Timg + (size_t)(rowok2 ? gr2 : 0) * IMG_W;
        const bool fast2 = rowok2 && (col02 >= 0) && (col02 + 20 <= IMG_W);
        const int wb2 = r2 * STRIDE + (cg2 << 2);
        if (fast2) PROC_UNIT_FAST(rowP2, rowT2, col02, wb2);
        else       PROC_UNIT_EW(rowP2, rowT2, col02, rowok2, wb2);
    }
    __syncthreads();

    // ---- stage 2: vertical 11-tap (streaming from LDS) + SSIM formula ----
    const int col = tid & 31;
    const int rg0 = tid >> 5;          // 0..7

    const float C1 = 1.0e-4f;   // (0.01*1)^2
    const float C2 = 9.0e-4f;   // (0.03*1)^2
    float lsum = 0.0f;

    #pragma unroll
    for (int pass = 0; pass < 2; ++pass) {
        const int rg = rg0 + (pass << 3);   // 0..15, rows rg*4 .. rg*4+3

        float sau[4], sav[4], sauu[4], savv[4];
        #pragma unroll
        for (int k = 0; k < 4; ++k) {
            sau[k] = 0.f; sav[k] = 0.f; sauu[k] = 0.f; savv[k] = 0.f;
        }

        #pragma unroll
        for (int i = 0; i < 14; ++i) {
            const int idx = (rg * 4 + i) * STRIDE + col;
            const float2 hu = Hu[idx];
            const float2 hv = Hv[idx];
            #pragma unroll
            for (int k = 0; k < 4; ++k) {
                const int j = i - k;                   // compile-time tap
                if (j >= 0 && j < KS) {
                    sau [k] = fmaf(GW(j), hu.x, sau [k]);
                    sauu[k] = fmaf(GW(j), hu.y, sauu[k]);
                    sav [k] = fmaf(GW(j), hv.x, sav [k]);
                    savv[k] = fmaf(GW(j), hv.y, savv[k]);
                }
            }
        }

        #pragma unroll
        for (int k = 0; k < 4; ++k) {
            const float u2 = sau[k] * sau[k];   // muu^2
            const float v2 = sav[k] * sav[k];   // muv^2
            const float A  = u2 - v2;           // 4*mux*muy
            const float B  = u2 + v2;           // 2*(mux^2+muy^2)
            const float Cd = sauu[k] - savv[k]; // 4*conv(xy)
            const float Cs = sauu[k] + savv[k]; // 2*(conv(x^2)+conv(y^2))
            const float num1 = fmaf(0.5f, A, C1);        // 2 mux muy + C1
            const float den1 = fmaf(0.5f, B, C1);        // mux^2+muy^2 + C1
            const float num2 = fmaf(0.5f, Cd - A, C2);   // 2 sigma_xy + C2
            const float den2 = fmaf(0.5f, Cs - B, C2);   // sx2+sy2 + C2
            lsum = fmaf(num1 * num2, __builtin_amdgcn_rcpf(den1 * den2), lsum);
        }
    }

    // ---- block reduction ----
    #pragma unroll
    for (int off = 32; off > 0; off >>= 1)
        lsum += __shfl_down(lsum, off, 64);

    const int lane = tid & 63;
    const int wid  = tid >> 6;
    if (lane == 0) wsum[wid] = lsum;
    __syncthreads();
    if (tid == 0)
        partial[bid] = wsum[0] + wsum[1] + wsum[2] + wsum[3];
}

// ---------------- final reduction ----------------
__global__ __launch_bounds__(1024) void ssim_reduce_kernel(
    const float* __restrict__ partial, int n, float* __restrict__ out)
{
    const int tid = threadIdx.x;
    double s = 0.0;
    for (int i = tid; i < n; i += 1024) s += (double)partial[i];

    #pragma unroll
    for (int off = 32; off > 0; off >>= 1)
        s += __shfl_down(s, off, 64);

    __shared__ double dsum[16];
    const int lane = tid & 63;
    const int wid  = tid >> 6;
    if (lane == 0) dsum[wid] = s;
    __syncthreads();
    if (tid == 0) {
        double total = 0.0;
        #pragma unroll
        for (int w = 0; w < 16; ++w) total += dsum[w];
        out[0] = (float)(1.0 - total / TOTAL_N);
    }
}

extern "C" void kernel_launch(void* const* d_in, const int* in_sizes, int n_in,
                              void* d_out, int out_size, void* d_ws, size_t ws_size,
                              hipStream_t stream) {
    const float* pred = (const float*)d_in[0];
    const float* targ = (const float*)d_in[1];
    const float* k2d  = (const float*)d_in[2];
    float* out = (float*)d_out;
    float* ws  = (float*)d_ws;   // NBLOCKS partial sums

    ssim_tile_kernel<<<NBLOCKS, 256, 0, stream>>>(pred, targ, k2d, ws);
    ssim_reduce_kernel<<<1, 1024, 0, stream>>>(ws, NBLOCKS, out);
}

// Round 17
// 123.898 us; speedup vs baseline: 1.1907x; 1.1907x over previous
//
#include <hip/hip_runtime.h>
#include <math.h>

#define IMG_H 512
#define IMG_W 512
#define N_IMG 96            // 32 * 3
#define TW 32               // tile width (output cols)
#define TH 64               // tile height (output rows)
#define KS 11
#define IN_ROWS 74          // TH + 10
#define NUNITS (IN_ROWS * 8)    // 592 horizontal-conv units (4 px each)
#define STRIDE 33           // LDS row stride in float2 units
#define PLANE (IN_ROWS * STRIDE)   // 2442 float2
#define NBLOCKS (N_IMG * (IMG_W / TW) * (IMG_H / TH))   // 12288
#define TOTAL_N 25165824.0  // 32*3*512*512

// Round-17: 512-THREAD BLOCKS (8 waves/block). Cross-round evidence:
// r11/r12 (occ 54%) == r14 (occ 34%) == ~140us; true VALU ~28%; all pipes
// <30% utilized. The CP grants residency per BLOCK (~2.7-4.3 blocks/CU in
// every round); with 4-wave blocks that caps waves/CU at ~11-17. Bigger
// blocks put more waves on the CU at the same block residency:
//   512 thr x 4 blocks/CU (LDS 39.1KB) = 32 waves/CU = HW max.
// Per-thread work halves (stage 1: 1 unit + 80 threads do a 2nd; stage 2:
// single pass rg=tid>>5). Internals byte-identical to r14 (gather-then-
// convolve, u/v 4-map, stride-33 float2 planes, 0-ish conflicts, no spill).
// (512,4) keeps VGPR cap 128 -> no r8-style allocator collapse (need ~52).

#define GW(j) g6[(j) <= 5 ? (j) : 10 - (j)]

__global__ __launch_bounds__(512, 4) void ssim_tile_kernel(
    const float* __restrict__ pred, const float* __restrict__ targ,
    const float* __restrict__ k2d, float* __restrict__ partial)
{
    __shared__ float2 Hu[PLANE];
    __shared__ float2 Hv[PLANE];
    __shared__ float wsum[8];

    const int tid = threadIdx.x;
    const int bid = blockIdx.x;
    const int img = bid >> 7;          // 128 tiles per image
    const int tin = bid & 127;
    const int ty  = tin >> 4;          // 0..7
    const int tx  = tin & 15;          // 0..15
    const int y0  = ty * TH;
    const int x0  = tx * TW;

    // exact 1D gaussian from the 2D kernel row 5: k2d[5][j] = g5*g[j]; symmetric
    float g6[6];
    {
        const float inv = rsqrtf(k2d[5 * KS + 5]);
        #pragma unroll
        for (int j = 0; j < 6; ++j) g6[j] = k2d[5 * KS + j] * inv;
    }

    const float* __restrict__ Pimg = pred + (size_t)img * (IMG_H * IMG_W);
    const float* __restrict__ Timg = targ + (size_t)img * (IMG_H * IMG_W);

    // ---- stage 1: horizontal 11-tap on u,v,u^2,v^2 -> packed LDS planes ----
    #pragma unroll
    for (int b = 0; b < 2; ++b) {
        const int u = tid + (b << 9);          // b=0: all 512; b=1: tid<80
        if (u < NUNITS) {
            const int r    = u >> 3;           // 0..73
            const int cg   = u & 7;            // 0..7
            const int gr   = y0 - 5 + r;
            const int col0 = x0 + (cg << 2) - 8;   // 16B-aligned window start
            const bool rowok = ((unsigned)gr < (unsigned)IMG_H);
            const float* rowP = Pimg + (size_t)(rowok ? gr : 0) * IMG_W;
            const float* rowT = Timg + (size_t)(rowok ? gr : 0) * IMG_W;

            // used window elems are 3..16 -> uw/vw[0..13]
            float uw[14], vw[14];
            if (rowok && col0 >= 0 && col0 + 20 <= IMG_W) {
                #pragma unroll
                for (int q = 0; q < 5; ++q) {
                    const float4 vp = *(const float4*)(rowP + col0 + 4 * q);
                    const float4 vt = *(const float4*)(rowT + col0 + 4 * q);
                    const float pe[4] = {vp.x, vp.y, vp.z, vp.w};
                    const float te[4] = {vt.x, vt.y, vt.z, vt.w};
                    #pragma unroll
                    for (int e = 0; e < 4; ++e) {
                        const int ge = 4 * q + e;          // compile-time
                        if (ge >= 3 && ge <= 16) {
                            uw[ge - 3] = pe[e] + te[e];
                            vw[ge - 3] = pe[e] - te[e];
                        }
                    }
                }
            } else {
                #pragma unroll
                for (int e = 3; e <= 16; ++e) {
                    const int c  = col0 + e;
                    const int cc = min(max(c, 0), IMG_W - 1);
                    const bool ok = rowok && (c >= 0) && (c < IMG_W);
                    const float pv = rowP[cc];
                    const float tv = rowT[cc];
                    uw[e - 3] = ok ? (pv + tv) : 0.0f;
                    vw[e - 3] = ok ? (pv - tv) : 0.0f;
                }
            }

            const int wb = r * STRIDE + (cg << 2);

            // u-maps: mu conv, square in place, second-moment conv, write
            {
                float au[4], auu[4];
                #pragma unroll
                for (int k = 0; k < 4; ++k) { au[k] = 0.f; }
                #pragma unroll
                for (int k = 0; k < 4; ++k) {
                    #pragma unroll
                    for (int j = 0; j < KS; ++j)
                        au[k] = fmaf(GW(j), uw[k + j], au[k]);
                }
                #pragma unroll
                for (int i = 0; i < 14; ++i) uw[i] *= uw[i];
                #pragma unroll
                for (int k = 0; k < 4; ++k) { auu[k] = 0.f; }
                #pragma unroll
                for (int k = 0; k < 4; ++k) {
                    #pragma unroll
                    for (int j = 0; j < KS; ++j)
                        auu[k] = fmaf(GW(j), uw[k + j], auu[k]);
                }
                #pragma unroll
                for (int e = 0; e < 4; ++e)
                    Hu[wb + e] = make_float2(au[e], auu[e]);
            }
            // v-maps
            {
                float av[4], avv[4];
                #pragma unroll
                for (int k = 0; k < 4; ++k) { av[k] = 0.f; }
                #pragma unroll
                for (int k = 0; k < 4; ++k) {
                    #pragma unroll
                    for (int j = 0; j < KS; ++j)
                        av[k] = fmaf(GW(j), vw[k + j], av[k]);
                }
                #pragma unroll
                for (int i = 0; i < 14; ++i) vw[i] *= vw[i];
                #pragma unroll
                for (int k = 0; k < 4; ++k) { avv[k] = 0.f; }
                #pragma unroll
                for (int k = 0; k < 4; ++k) {
                    #pragma unroll
                    for (int j = 0; j < KS; ++j)
                        avv[k] = fmaf(GW(j), vw[k + j], avv[k]);
                }
                #pragma unroll
                for (int e = 0; e < 4; ++e)
                    Hv[wb + e] = make_float2(av[e], avv[e]);
            }
        }
    }
    __syncthreads();

    // ---- stage 2: vertical 11-tap (streaming from LDS) + SSIM formula ----
    const int col = tid & 31;
    const int rg  = tid >> 5;          // 0..15, rows rg*4 .. rg*4+3

    const float C1 = 1.0e-4f;   // (0.01*1)^2
    const float C2 = 9.0e-4f;   // (0.03*1)^2
    float lsum = 0.0f;

    {
        float sau[4], sav[4], sauu[4], savv[4];
        #pragma unroll
        for (int k = 0; k < 4; ++k) {
            sau[k] = 0.f; sav[k] = 0.f; sauu[k] = 0.f; savv[k] = 0.f;
        }

        #pragma unroll
        for (int i = 0; i < 14; ++i) {
            const int idx = (rg * 4 + i) * STRIDE + col;
            const float2 hu = Hu[idx];
            const float2 hv = Hv[idx];
            #pragma unroll
            for (int k = 0; k < 4; ++k) {
                const int j = i - k;                   // compile-time tap
                if (j >= 0 && j < KS) {
                    sau [k] = fmaf(GW(j), hu.x, sau [k]);
                    sauu[k] = fmaf(GW(j), hu.y, sauu[k]);
                    sav [k] = fmaf(GW(j), hv.x, sav [k]);
                    savv[k] = fmaf(GW(j), hv.y, savv[k]);
                }
            }
        }

        #pragma unroll
        for (int k = 0; k < 4; ++k) {
            const float u2 = sau[k] * sau[k];   // muu^2
            const float v2 = sav[k] * sav[k];   // muv^2
            const float A  = u2 - v2;           // 4*mux*muy
            const float B  = u2 + v2;           // 2*(mux^2+muy^2)
            const float Cd = sauu[k] - savv[k]; // 4*conv(xy)
            const float Cs = sauu[k] + savv[k]; // 2*(conv(x^2)+conv(y^2))
            const float num1 = fmaf(0.5f, A, C1);        // 2 mux muy + C1
            const float den1 = fmaf(0.5f, B, C1);        // mux^2+muy^2 + C1
            const float num2 = fmaf(0.5f, Cd - A, C2);   // 2 sigma_xy + C2
            const float den2 = fmaf(0.5f, Cs - B, C2);   // sx2+sy2 + C2
            lsum = fmaf(num1 * num2, __builtin_amdgcn_rcpf(den1 * den2), lsum);
        }
    }

    // ---- block reduction (8 waves) ----
    #pragma unroll
    for (int off = 32; off > 0; off >>= 1)
        lsum += __shfl_down(lsum, off, 64);

    const int lane = tid & 63;
    const int wid  = tid >> 6;         // 0..7
    if (lane == 0) wsum[wid] = lsum;
    __syncthreads();
    if (tid == 0) {
        float s = 0.0f;
        #pragma unroll
        for (int w = 0; w < 8; ++w) s += wsum[w];
        partial[bid] = s;
    }
}

// ---------------- final reduction ----------------
__global__ __launch_bounds__(1024) void ssim_reduce_kernel(
    const float* __restrict__ partial, int n, float* __restrict__ out)
{
    const int tid = threadIdx.x;
    double s = 0.0;
    for (int i = tid; i < n; i += 1024) s += (double)partial[i];

    #pragma unroll
    for (int off = 32; off > 0; off >>= 1)
        s += __shfl_down(s, off, 64);

    __shared__ double dsum[16];
    const int lane = tid & 63;
    const int wid  = tid >> 6;
    if (lane == 0) dsum[wid] = s;
    __syncthreads();
    if (tid == 0) {
        double total = 0.0;
        #pragma unroll
        for (int w = 0; w < 16; ++w) total += dsum[w];
        out[0] = (float)(1.0 - total / TOTAL_N);
    }
}

extern "C" void kernel_launch(void* const* d_in, const int* in_sizes, int n_in,
                              void* d_out, int out_size, void* d_ws, size_t ws_size,
                              hipStream_t stream) {
    const float* pred = (const float*)d_in[0];
    const float* targ = (const float*)d_in[1];
    const float* k2d  = (const float*)d_in[2];
    float* out = (float*)d_out;
    float* ws  = (float*)d_ws;   // NBLOCKS partial sums

    ssim_tile_kernel<<<NBLOCKS, 512, 0, stream>>>(pred, targ, k2d, ws);
    ssim_reduce_kernel<<<1, 1024, 0, stream>>>(ws, NBLOCKS, out);
}

// Round 18
// 117.454 us; speedup vs baseline: 1.2560x; 1.0549x over previous
//
#include <hip/hip_runtime.h>
#include <math.h>

#define IMG_H 512
#define IMG_W 512
#define N_IMG 96            // 32 * 3
#define TW 32               // tile width (output cols)
#define TH 128              // tile height (output rows)  [r18: was 64]
#define KS 11
#define IN_ROWS 138         // TH + 10
#define NUNITS (IN_ROWS * 8)    // 1104 horizontal-conv units (4 px each)
#define STRIDE 33           // LDS row stride in float2 units
#define PLANE (IN_ROWS * STRIDE)   // 4554 float2
#define NBLOCKS (N_IMG * (IMG_W / TW) * (IMG_H / TH))   // 96*16*4 = 6144
#define TOTAL_N 25165824.0  // 32*3*512*512

// Round-18: 1024-THREAD BLOCKS (16 waves). r17 confirmed the lever: CP keeps
// ~2.4 blocks/CU resident regardless of block size, so waves/CU scales with
// block size (512thr -> occ 59.5%, 124us). Endpoint: 1024 threads, TH=128.
//   LDS = 2 planes * 4554 * 8B = 72.9KB -> exactly 2 blocks/CU (145.7KB),
//   and CP has always granted >=2.4 -> 2 resident = 32 waves/CU = HW MAX.
// Halo overhead 1.156 -> 1.078. (1024,8): VGPR cap 64, kernel needs ~32.
// Internals byte-identical to r17 (u/v 4-map, gather-then-convolve,
// stride-33 float2 planes, ~0 conflicts, no spill).

#define GW(j) g6[(j) <= 5 ? (j) : 10 - (j)]

__global__ __launch_bounds__(1024, 8) void ssim_tile_kernel(
    const float* __restrict__ pred, const float* __restrict__ targ,
    const float* __restrict__ k2d, float* __restrict__ partial)
{
    __shared__ float2 Hu[PLANE];
    __shared__ float2 Hv[PLANE];
    __shared__ float wsum[16];

    const int tid = threadIdx.x;
    const int bid = blockIdx.x;
    const int img = bid >> 6;          // 64 tiles per image
    const int tin = bid & 63;
    const int ty  = tin >> 4;          // 0..3
    const int tx  = tin & 15;          // 0..15
    const int y0  = ty * TH;
    const int x0  = tx * TW;

    // exact 1D gaussian from the 2D kernel row 5: k2d[5][j] = g5*g[j]; symmetric
    float g6[6];
    {
        const float inv = rsqrtf(k2d[5 * KS + 5]);
        #pragma unroll
        for (int j = 0; j < 6; ++j) g6[j] = k2d[5 * KS + j] * inv;
    }

    const float* __restrict__ Pimg = pred + (size_t)img * (IMG_H * IMG_W);
    const float* __restrict__ Timg = targ + (size_t)img * (IMG_H * IMG_W);

    // ---- stage 1: horizontal 11-tap on u,v,u^2,v^2 -> packed LDS planes ----
    #pragma unroll
    for (int b = 0; b < 2; ++b) {
        const int u = tid + (b << 10);         // b=0: all 1024; b=1: tid<80
        if (u < NUNITS) {
            const int r    = u >> 3;           // 0..137
            const int cg   = u & 7;            // 0..7
            const int gr   = y0 - 5 + r;
            const int col0 = x0 + (cg << 2) - 8;   // 16B-aligned window start
            const bool rowok = ((unsigned)gr < (unsigned)IMG_H);
            const float* rowP = Pimg + (size_t)(rowok ? gr : 0) * IMG_W;
            const float* rowT = Timg + (size_t)(rowok ? gr : 0) * IMG_W;

            // used window elems are 3..16 -> uw/vw[0..13]
            float uw[14], vw[14];
            if (rowok && col0 >= 0 && col0 + 20 <= IMG_W) {
                #pragma unroll
                for (int q = 0; q < 5; ++q) {
                    const float4 vp = *(const float4*)(rowP + col0 + 4 * q);
                    const float4 vt = *(const float4*)(rowT + col0 + 4 * q);
                    const float pe[4] = {vp.x, vp.y, vp.z, vp.w};
                    const float te[4] = {vt.x, vt.y, vt.z, vt.w};
                    #pragma unroll
                    for (int e = 0; e < 4; ++e) {
                        const int ge = 4 * q + e;          // compile-time
                        if (ge >= 3 && ge <= 16) {
                            uw[ge - 3] = pe[e] + te[e];
                            vw[ge - 3] = pe[e] - te[e];
                        }
                    }
                }
            } else {
                #pragma unroll
                for (int e = 3; e <= 16; ++e) {
                    const int c  = col0 + e;
                    const int cc = min(max(c, 0), IMG_W - 1);
                    const bool ok = rowok && (c >= 0) && (c < IMG_W);
                    const float pv = rowP[cc];
                    const float tv = rowT[cc];
                    uw[e - 3] = ok ? (pv + tv) : 0.0f;
                    vw[e - 3] = ok ? (pv - tv) : 0.0f;
                }
            }

            const int wb = r * STRIDE + (cg << 2);

            // u-maps: mu conv, square in place, second-moment conv, write
            {
                float au[4], auu[4];
                #pragma unroll
                for (int k = 0; k < 4; ++k) { au[k] = 0.f; }
                #pragma unroll
                for (int k = 0; k < 4; ++k) {
                    #pragma unroll
                    for (int j = 0; j < KS; ++j)
                        au[k] = fmaf(GW(j), uw[k + j], au[k]);
                }
                #pragma unroll
                for (int i = 0; i < 14; ++i) uw[i] *= uw[i];
                #pragma unroll
                for (int k = 0; k < 4; ++k) { auu[k] = 0.f; }
                #pragma unroll
                for (int k = 0; k < 4; ++k) {
                    #pragma unroll
                    for (int j = 0; j < KS; ++j)
                        auu[k] = fmaf(GW(j), uw[k + j], auu[k]);
                }
                #pragma unroll
                for (int e = 0; e < 4; ++e)
                    Hu[wb + e] = make_float2(au[e], auu[e]);
            }
            // v-maps
            {
                float av[4], avv[4];
                #pragma unroll
                for (int k = 0; k < 4; ++k) { av[k] = 0.f; }
                #pragma unroll
                for (int k = 0; k < 4; ++k) {
                    #pragma unroll
                    for (int j = 0; j < KS; ++j)
                        av[k] = fmaf(GW(j), vw[k + j], av[k]);
                }
                #pragma unroll
                for (int i = 0; i < 14; ++i) vw[i] *= vw[i];
                #pragma unroll
                for (int k = 0; k < 4; ++k) { avv[k] = 0.f; }
                #pragma unroll
                for (int k = 0; k < 4; ++k) {
                    #pragma unroll
                    for (int j = 0; j < KS; ++j)
                        avv[k] = fmaf(GW(j), vw[k + j], avv[k]);
                }
                #pragma unroll
                for (int e = 0; e < 4; ++e)
                    Hv[wb + e] = make_float2(av[e], avv[e]);
            }
        }
    }
    __syncthreads();

    // ---- stage 2: vertical 11-tap (streaming from LDS) + SSIM formula ----
    const int col = tid & 31;
    const int rg  = tid >> 5;          // 0..31, rows rg*4 .. rg*4+3

    const float C1 = 1.0e-4f;   // (0.01*1)^2
    const float C2 = 9.0e-4f;   // (0.03*1)^2
    float lsum = 0.0f;

    {
        float sau[4], sav[4], sauu[4], savv[4];
        #pragma unroll
        for (int k = 0; k < 4; ++k) {
            sau[k] = 0.f; sav[k] = 0.f; sauu[k] = 0.f; savv[k] = 0.f;
        }

        #pragma unroll
        for (int i = 0; i < 14; ++i) {
            const int idx = (rg * 4 + i) * STRIDE + col;
            const float2 hu = Hu[idx];
            const float2 hv = Hv[idx];
            #pragma unroll
            for (int k = 0; k < 4; ++k) {
                const int j = i - k;                   // compile-time tap
                if (j >= 0 && j < KS) {
                    sau [k] = fmaf(GW(j), hu.x, sau [k]);
                    sauu[k] = fmaf(GW(j), hu.y, sauu[k]);
                    sav [k] = fmaf(GW(j), hv.x, sav [k]);
                    savv[k] = fmaf(GW(j), hv.y, savv[k]);
                }
            }
        }

        #pragma unroll
        for (int k = 0; k < 4; ++k) {
            const float u2 = sau[k] * sau[k];   // muu^2
            const float v2 = sav[k] * sav[k];   // muv^2
            const float A  = u2 - v2;           // 4*mux*muy
            const float B  = u2 + v2;           // 2*(mux^2+muy^2)
            const float Cd = sauu[k] - savv[k]; // 4*conv(xy)
            const float Cs = sauu[k] + savv[k]; // 2*(conv(x^2)+conv(y^2))
            const float num1 = fmaf(0.5f, A, C1);        // 2 mux muy + C1
            const float den1 = fmaf(0.5f, B, C1);        // mux^2+muy^2 + C1
            const float num2 = fmaf(0.5f, Cd - A, C2);   // 2 sigma_xy + C2
            const float den2 = fmaf(0.5f, Cs - B, C2);   // sx2+sy2 + C2
            lsum = fmaf(num1 * num2, __builtin_amdgcn_rcpf(den1 * den2), lsum);
        }
    }

    // ---- block reduction (16 waves) ----
    #pragma unroll
    for (int off = 32; off > 0; off >>= 1)
        lsum += __shfl_down(lsum, off, 64);

    const int lane = tid & 63;
    const int wid  = tid >> 6;         // 0..15
    if (lane == 0) wsum[wid] = lsum;
    __syncthreads();
    if (tid == 0) {
        float s = 0.0f;
        #pragma unroll
        for (int w = 0; w < 16; ++w) s += wsum[w];
        partial[bid] = s;
    }
}

// ---------------- final reduction ----------------
__global__ __launch_bounds__(1024) void ssim_reduce_kernel(
    const float* __restrict__ partial, int n, float* __restrict__ out)
{
    const int tid = threadIdx.x;
    double s = 0.0;
    for (int i = tid; i < n; i += 1024) s += (double)partial[i];

    #pragma unroll
    for (int off = 32; off > 0; off >>= 1)
        s += __shfl_down(s, off, 64);

    __shared__ double dsum[16];
    const int lane = tid & 63;
    const int wid  = tid >> 6;
    if (lane == 0) dsum[wid] = s;
    __syncthreads();
    if (tid == 0) {
        double total = 0.0;
        #pragma unroll
        for (int w = 0; w < 16; ++w) total += dsum[w];
        out[0] = (float)(1.0 - total / TOTAL_N);
    }
}

extern "C" void kernel_launch(void* const* d_in, const int* in_sizes, int n_in,
                              void* d_out, int out_size, void* d_ws, size_t ws_size,
                              hipStream_t stream) {
    const float* pred = (const float*)d_in[0];
    const float* targ = (const float*)d_in[1];
    const float* k2d  = (const float*)d_in[2];
    float* out = (float*)d_out;
    float* ws  = (float*)d_ws;   // NBLOCKS partial sums

    ssim_tile_kernel<<<NBLOCKS, 1024, 0, stream>>>(pred, targ, k2d, ws);
    ssim_reduce_kernel<<<1, 1024, 0, stream>>>(ws, NBLOCKS, out);
}